// Round 4
// baseline (52.984 us; speedup 1.0000x reference)
//
#include <hip/hip_runtime.h>
#include <hip/hip_cooperative_groups.h>

namespace cg = cooperative_groups;

// Problem constants from the reference (fixed problem instance).
#define BB 32      // batch
#define KK 8       // channels
#define HH 512     // height
#define WW 512     // width
#define SS 50      // sample count
#define HID 64     // hidden dim
#define CTX 71     // 9*K - 1

#define NBLK 400   // 400 blocks x 4 waves = 1600 pairs
#define TPB  256
#define PPB  4     // pairs (waves) per block

// Fused single-dispatch kernel: phase 1 computes one (b,s) pair per wave,
// grid-sync, phase 2 (block 0) reduces the 1600 flags to the mean.
__global__ void __launch_bounds__(TPB)
le_fused_kernel(const float* __restrict__ z,
                const float* __restrict__ W1,
                const float* __restrict__ b1,
                const float* __restrict__ W2,
                const float* __restrict__ b2,
                const int*   __restrict__ b_idx,
                const int*   __restrict__ i_idx,
                const int*   __restrict__ j_idx,
                float*       __restrict__ ws,
                float*       __restrict__ out)
{
    const int wave = threadIdx.x >> 6;           // 0..3
    const int lane = threadIdx.x & 63;           // 0..63
    const int bs   = blockIdx.x * PPB + wave;    // 0..1599
    const int b    = bs / SS;
    const int s    = bs - b * SS;

    __shared__ float full[PPB][9 * KK];          // 72 gathered values per wave

    // Block(wave)-uniform sample indices.
    const int i0   = i_idx[s];
    const int j0   = j_idx[s];
    const int bsel = b_idx[s];
    const int rm   = 4 * KK + bsel;              // removed (center) position

    // Gather 72 neighborhood values. p = n*KK + k. Lane covers p=lane;
    // lanes 0..7 additionally cover p=64+lane (n=8: di=+1,dj=+1).
    {
        const int n  = lane >> 3;
        const int k  = lane & 7;
        const int ni = (i0 + (n / 3) - 1) & (HH - 1);   // torus wrap
        const int nj = (j0 + (n % 3) - 1) & (WW - 1);
        full[wave][lane] = z[(((b * KK + k) * HH + ni) * WW) + nj];
    }
    if (lane < 8) {
        const int ni = (i0 + 1) & (HH - 1);
        const int nj = (j0 + 1) & (WW - 1);
        full[wave][64 + lane] = z[(((b * KK + lane) * HH + ni) * WW) + nj];
    }
    // Wave-private LDS row; same-wave write->read ordering is handled by
    // compiler-inserted lgkmcnt waits (no __syncthreads needed here).

    // Matvec: lane owns hidden unit `lane`; W1 loads stay in-loop (R1 form —
    // pipelined by the 8x unroll, measured faster than full register prefetch).
    float acc = b1[lane];
    #pragma unroll 8
    for (int t = 0; t < CTX; ++t) {
        const int src = t + (t >= rm ? 1 : 0);   // skip removed element
        acc = fmaf(full[wave][src], W1[t * HID + lane], acc);
    }
    const float hv      = acc > 0.0f ? acc : 0.0f;
    float       contrib = hv * W2[lane];

    #pragma unroll
    for (int off = 32; off > 0; off >>= 1)
        contrib += __shfl_down(contrib, off);

    if (lane == 0) {
        const float logit  = contrib + b2[0];
        const float pred   = logit > 0.0f ? 1.0f : 0.0f;
        const float actual = full[wave][rm];
        ws[bs] = (pred != actual) ? 1.0f : 0.0f;
    }

    cg::this_grid().sync();

    // Phase 2: block 0 reduces all 1600 flags (L2-hot after phase 1).
    if (blockIdx.x == 0) {
        float ssum = 0.0f;
        for (int i = threadIdx.x; i < BB * SS; i += TPB) ssum += ws[i];

        #pragma unroll
        for (int off = 32; off > 0; off >>= 1)
            ssum += __shfl_down(ssum, off);

        __shared__ float wsum[PPB];
        if (lane == 0) wsum[wave] = ssum;
        __syncthreads();
        if (threadIdx.x == 0)
            out[0] = (wsum[0] + wsum[1] + wsum[2] + wsum[3])
                     * (1.0f / (float)(BB * SS));
    }
}

extern "C" void kernel_launch(void* const* d_in, const int* in_sizes, int n_in,
                              void* d_out, int out_size, void* d_ws, size_t ws_size,
                              hipStream_t stream)
{
    const float* z     = (const float*)d_in[0];
    const float* W1    = (const float*)d_in[1];
    const float* b1    = (const float*)d_in[2];
    const float* W2    = (const float*)d_in[3];
    const float* b2    = (const float*)d_in[4];
    const int*   b_idx = (const int*)d_in[5];
    const int*   i_idx = (const int*)d_in[6];
    const int*   j_idx = (const int*)d_in[7];

    float* out = (float*)d_out;
    float* ws  = (float*)d_ws;   // BB*SS floats = 6.4 KB scratch

    void* args[] = {
        (void*)&z, (void*)&W1, (void*)&b1, (void*)&W2, (void*)&b2,
        (void*)&b_idx, (void*)&i_idx, (void*)&j_idx, (void*)&ws, (void*)&out
    };
    hipLaunchCooperativeKernel((const void*)le_fused_kernel,
                               dim3(NBLK), dim3(TPB), args, 0, stream);
}

// Round 5
// 23.427 us; speedup vs baseline: 2.2617x; 2.2617x over previous
//
#include <hip/hip_runtime.h>

// Problem constants from the reference (fixed problem instance).
#define BB 32      // batch
#define KK 8       // channels
#define HH 512     // height
#define WW 512     // width
#define SS 50      // sample count
#define HID 64     // hidden dim
#define CTX 71     // 9*K - 1

#define TPB  256
#define PPB  4                   // pairs (waves) per block
#define NBLK (BB * SS / PPB)     // 400 blocks

// Single dispatch, no grid sync: each block computes PPB pairs, publishes a
// per-block error count, and the last-arriving block reduces the 400 partials.
__global__ void __launch_bounds__(TPB)
le_fused_kernel(const float* __restrict__ z,
                const float* __restrict__ W1,
                const float* __restrict__ b1,
                const float* __restrict__ W2,
                const float* __restrict__ b2,
                const int*   __restrict__ b_idx,
                const int*   __restrict__ i_idx,
                const int*   __restrict__ j_idx,
                float*       __restrict__ partial,   // ws: NBLK floats
                int*         __restrict__ cnt,       // ws: arrival counter (memset 0)
                float*       __restrict__ out)
{
    const int wave = threadIdx.x >> 6;           // 0..3
    const int lane = threadIdx.x & 63;           // 0..63
    const int bs   = blockIdx.x * PPB + wave;    // 0..1599
    const int b    = bs / SS;
    const int s    = bs - b * SS;

    __shared__ float full[PPB][9 * KK];          // 72 gathered values per wave
    __shared__ float sflag[PPB];
    __shared__ int   is_last;

    // Wave-uniform sample indices (scalar loads).
    const int i0   = i_idx[s];
    const int j0   = j_idx[s];
    const int bsel = b_idx[s];
    const int rm   = 4 * KK + bsel;              // removed (center) position

    // Gather 72 neighborhood values. p = n*KK + k. Lane covers p=lane;
    // lanes 0..7 additionally cover p=64+lane (n=8: di=+1,dj=+1).
    {
        const int n  = lane >> 3;
        const int k  = lane & 7;
        const int ni = (i0 + (n / 3) - 1) & (HH - 1);   // torus wrap
        const int nj = (j0 + (n % 3) - 1) & (WW - 1);
        full[wave][lane] = z[(((b * KK + k) * HH + ni) * WW) + nj];
    }
    if (lane < 8) {
        const int ni = (i0 + 1) & (HH - 1);
        const int nj = (j0 + 1) & (WW - 1);
        full[wave][64 + lane] = z[(((b * KK + lane) * HH + ni) * WW) + nj];
    }
    // Wave-private LDS row: same-wave write->read handled by lgkmcnt waits.

    // Matvec: lane owns hidden unit `lane`; in-loop W1 reads (R1 form — faster
    // than full register prefetch, measured R1 vs R3).
    float acc = b1[lane];
    #pragma unroll 8
    for (int t = 0; t < CTX; ++t) {
        const int src = t + (t >= rm ? 1 : 0);   // skip removed element
        acc = fmaf(full[wave][src], W1[t * HID + lane], acc);
    }
    const float hv      = acc > 0.0f ? acc : 0.0f;
    float       contrib = hv * W2[lane];

    #pragma unroll
    for (int off = 32; off > 0; off >>= 1)
        contrib += __shfl_down(contrib, off);

    if (lane == 0) {
        const float logit = contrib + b2[0];
        const float pred  = logit > 0.0f ? 1.0f : 0.0f;
        sflag[wave] = (pred != full[wave][rm]) ? 1.0f : 0.0f;
    }
    __syncthreads();

    // Publish per-block error count (exact small integer), then arrive.
    if (threadIdx.x == 0) {
        const float blk = sflag[0] + sflag[1] + sflag[2] + sflag[3];
        __hip_atomic_store(&partial[blockIdx.x], blk,
                           __ATOMIC_RELEASE, __HIP_MEMORY_SCOPE_AGENT);
        const int old = __hip_atomic_fetch_add(cnt, 1, __ATOMIC_ACQ_REL,
                                               __HIP_MEMORY_SCOPE_AGENT);
        is_last = (old == NBLK - 1);
    }
    __syncthreads();

    // Last-arriving block reduces the 400 partials (fixed order -> bitwise
    // deterministic regardless of which block executes this).
    if (is_last) {
        float ssum = 0.0f;
        #pragma unroll
        for (int i = threadIdx.x; i < NBLK; i += TPB)   // 2 loads/thread
            ssum += __hip_atomic_load(&partial[i], __ATOMIC_RELAXED,
                                      __HIP_MEMORY_SCOPE_AGENT);
        #pragma unroll
        for (int off = 32; off > 0; off >>= 1)
            ssum += __shfl_down(ssum, off);

        __shared__ float wsum[PPB];
        if (lane == 0) wsum[wave] = ssum;
        __syncthreads();
        if (threadIdx.x == 0)
            out[0] = (wsum[0] + wsum[1] + wsum[2] + wsum[3])
                     * (1.0f / (float)(BB * SS));
    }
}

extern "C" void kernel_launch(void* const* d_in, const int* in_sizes, int n_in,
                              void* d_out, int out_size, void* d_ws, size_t ws_size,
                              hipStream_t stream)
{
    const float* z     = (const float*)d_in[0];
    const float* W1    = (const float*)d_in[1];
    const float* b1    = (const float*)d_in[2];
    const float* W2    = (const float*)d_in[3];
    const float* b2    = (const float*)d_in[4];
    const int*   b_idx = (const int*)d_in[5];
    const int*   i_idx = (const int*)d_in[6];
    const int*   j_idx = (const int*)d_in[7];

    float* out     = (float*)d_out;
    float* partial = (float*)d_ws;                       // NBLK floats
    int*   cnt     = (int*)((char*)d_ws + NBLK * sizeof(float));

    hipMemsetAsync(cnt, 0, sizeof(int), stream);         // graph memset node

    le_fused_kernel<<<NBLK, TPB, 0, stream>>>(z, W1, b1, W2, b2,
                                              b_idx, i_idx, j_idx,
                                              partial, cnt, out);
}

// Round 6
// 11.705 us; speedup vs baseline: 4.5268x; 2.0015x over previous
//
#include <hip/hip_runtime.h>

// Problem constants from the reference (fixed problem instance).
#define BB 32      // batch
#define KK 8       // channels
#define HH 512     // height
#define WW 512     // width
#define SS 50      // sample count
#define HID 64     // hidden dim
#define CTX 71     // 9*K - 1

#define NPB  4                   // pairs (waves) per block
#define TPB  (NPB * 64)          // 256 threads
#define NBLK (BB * SS / NPB)     // 400 blocks
#define RTPB 128                 // reduce-kernel threads

// K1: 4 (b,s) pairs per 256-thread block. W1 staged once per block into LDS
// (float4, overlapped with the HBM z-gather); matvec is pure LDS + FMA.
// Writes one per-block partial error count (exact small integer as float).
__global__ void __launch_bounds__(TPB)
le_core_kernel(const float* __restrict__ z,
               const float* __restrict__ W1,
               const float* __restrict__ b1,
               const float* __restrict__ W2,
               const float* __restrict__ b2,
               const int*   __restrict__ b_idx,
               const int*   __restrict__ i_idx,
               const int*   __restrict__ j_idx,
               float*       __restrict__ partial)
{
    const int wave = threadIdx.x >> 6;           // 0..3
    const int lane = threadIdx.x & 63;           // 0..63
    const int bs   = blockIdx.x * NPB + wave;    // 0..1599
    const int b    = bs / SS;
    const int s    = bs - b * SS;

    __shared__ float sW1[CTX * HID];             // 18176 B, shared by 4 waves
    __shared__ float sFull[NPB][9 * KK];         // 72 gathered values per wave
    __shared__ float sflag[NPB];

    // Wave-uniform sample indices (scalar loads).
    const int i0 = i_idx[s];
    const int j0 = j_idx[s];
    const int rm = 4 * KK + b_idx[s];            // removed (center) position

    // Issue the scattered z gather first (HBM latency, ~900 cy).
    // p = n*KK + k; lane covers p=lane, lanes 0..7 also p=64+lane (n=8).
    {
        const int n  = lane >> 3;
        const int k  = lane & 7;
        const int ni = (i0 + (n / 3) - 1) & (HH - 1);   // torus wrap
        const int nj = (j0 + (n % 3) - 1) & (WW - 1);
        sFull[wave][lane] = z[(((b * KK + k) * HH + ni) * WW) + nj];
    }
    if (lane < 8) {
        const int ni = (i0 + 1) & (HH - 1);
        const int nj = (j0 + 1) & (WW - 1);
        sFull[wave][64 + lane] = z[(((b * KK + lane) * HH + ni) * WW) + nj];
    }

    // Cooperative W1 -> LDS staging (float4, 1136 vec4s over 256 threads);
    // these loads fly concurrently with the z gather above.
    {
        const float4* s4 = (const float4*)W1;
        float4*       d4 = (float4*)sW1;
        for (int idx = threadIdx.x; idx < (CTX * HID) / 4; idx += TPB)
            d4[idx] = s4[idx];
    }
    __syncthreads();

    // Matvec: lane owns hidden unit `lane`. sW1 read is lane-consecutive
    // (conflict-free); sFull read is a wave-broadcast (free).
    float acc = b1[lane];
    #pragma unroll
    for (int t = 0; t < CTX; ++t) {
        const int src = t + (t >= rm ? 1 : 0);   // skip removed element
        acc = fmaf(sFull[wave][src], sW1[t * HID + lane], acc);
    }
    const float hv      = acc > 0.0f ? acc : 0.0f;
    float       contrib = hv * W2[lane];

    #pragma unroll
    for (int off = 32; off > 0; off >>= 1)
        contrib += __shfl_down(contrib, off);

    if (lane == 0) {
        const float logit = contrib + b2[0];
        const float pred  = logit > 0.0f ? 1.0f : 0.0f;
        sflag[wave] = (pred != sFull[wave][rm]) ? 1.0f : 0.0f;
    }
    __syncthreads();

    if (threadIdx.x == 0)
        partial[blockIdx.x] = sflag[0] + sflag[1] + sflag[2] + sflag[3];
}

// K2: reduce 400 per-block partials -> mean. Fixed summation order.
__global__ void __launch_bounds__(RTPB)
le_reduce_kernel(const float* __restrict__ partial, float* __restrict__ out)
{
    const int tid = threadIdx.x;                 // 0..127
    float ssum = 0.0f;
    for (int i = tid; i < NBLK; i += RTPB) ssum += partial[i];  // 4 rounds

    #pragma unroll
    for (int off = 32; off > 0; off >>= 1)
        ssum += __shfl_down(ssum, off);

    __shared__ float wsum[RTPB / 64];
    if ((tid & 63) == 0) wsum[tid >> 6] = ssum;
    __syncthreads();
    if (tid == 0)
        out[0] = (wsum[0] + wsum[1]) * (1.0f / (float)(BB * SS));
}

extern "C" void kernel_launch(void* const* d_in, const int* in_sizes, int n_in,
                              void* d_out, int out_size, void* d_ws, size_t ws_size,
                              hipStream_t stream)
{
    const float* z     = (const float*)d_in[0];
    const float* W1    = (const float*)d_in[1];
    const float* b1    = (const float*)d_in[2];
    const float* W2    = (const float*)d_in[3];
    const float* b2    = (const float*)d_in[4];
    const int*   b_idx = (const int*)d_in[5];
    const int*   i_idx = (const int*)d_in[6];
    const int*   j_idx = (const int*)d_in[7];

    float* out     = (float*)d_out;
    float* partial = (float*)d_ws;               // NBLK floats = 1.6 KB

    le_core_kernel<<<NBLK, TPB, 0, stream>>>(z, W1, b1, W2, b2,
                                             b_idx, i_idx, j_idx, partial);
    le_reduce_kernel<<<1, RTPB, 0, stream>>>(partial, out);
}

// Round 7
// 10.914 us; speedup vs baseline: 4.8547x; 1.0725x over previous
//
#include <hip/hip_runtime.h>

// Problem constants from the reference (fixed problem instance).
#define BB 32      // batch
#define KK 8       // channels
#define HH 512     // height
#define WW 512     // width
#define SS 50      // sample count
#define HID 64     // hidden dim
#define CTX 71     // 9*K - 1

#define NPB  8                   // pairs (waves) per block
#define TPB  (NPB * 64)          // 512 threads
#define NBLK (BB * SS / NPB)     // 200 blocks -> at most 1 block per CU

// K1: 8 (b,s) pairs per 512-thread block, one block per CU.
// z in {0,1} -> the 72-value context is captured as a wave-uniform bitmask
// via __ballot (lane p gathered position p). The matvec is then
// 71 x { conflict-free ds_read_b32 of W1 + mask-selected add } per lane,
// bitwise identical to fma with 0.0/1.0 context values.
__global__ void __launch_bounds__(TPB)
le_core_kernel(const float* __restrict__ z,
               const float* __restrict__ W1,
               const float* __restrict__ b1,
               const float* __restrict__ W2,
               const float* __restrict__ b2,
               const int*   __restrict__ b_idx,
               const int*   __restrict__ i_idx,
               const int*   __restrict__ j_idx,
               float*       __restrict__ partial)
{
    const int wave = threadIdx.x >> 6;           // 0..7
    const int lane = threadIdx.x & 63;           // 0..63
    const int bs   = blockIdx.x * NPB + wave;    // 0..1599
    const int b    = bs / SS;
    const int s    = bs - b * SS;

    __shared__ float sW1[CTX * HID];             // 18176 B, shared by 8 waves
    __shared__ float sflag[NPB];

    // Wave-uniform sample indices.
    const int i0 = i_idx[s];
    const int j0 = j_idx[s];
    const int rm = 4 * KK + b_idx[s];            // removed position, in [32,39]

    // Scattered z gather straight into registers (HBM latency ~900 cy).
    // Lane p holds neighborhood position p = n*KK + k; lanes 0..7 also 64+p.
    float z0, z1 = 0.0f;
    {
        const int n  = lane >> 3;
        const int k  = lane & 7;
        const int ni = (i0 + (n / 3) - 1) & (HH - 1);   // torus wrap
        const int nj = (j0 + (n % 3) - 1) & (WW - 1);
        z0 = z[(((b * KK + k) * HH + ni) * WW) + nj];
    }
    if (lane < 8) {
        const int ni = (i0 + 1) & (HH - 1);
        const int nj = (j0 + 1) & (WW - 1);
        z1 = z[(((b * KK + lane) * HH + ni) * WW) + nj];
    }

    // Cooperative W1 -> LDS staging (float4); flies concurrently with gather.
    {
        const float4* s4 = (const float4*)W1;
        float4*       d4 = (float4*)sW1;
        #pragma unroll
        for (int idx = threadIdx.x; idx < (CTX * HID) / 4; idx += TPB)
            d4[idx] = s4[idx];
    }

    // Context as a 72-bit wave-uniform mask.
    const unsigned long long mlo = __ballot(z0 > 0.5f);          // bits 0..63
    const unsigned long long mhi = __ballot(z1 > 0.5f) & 0xFFull; // bits 64..71

    const float actual = (float)((unsigned)(mlo >> rm) & 1u);    // rm < 64

    // Remove bit rm, shift upper bits down: 71-bit compressed mask.
    const unsigned __int128 M  = ((unsigned __int128)mhi << 64) | mlo;
    const unsigned __int128 lo = M & ((((unsigned __int128)1) << rm) - 1);
    const unsigned __int128 C  = lo | ((M >> (rm + 1)) << rm);
    const unsigned long long clo = (unsigned long long)C;
    const unsigned long long chi = (unsigned long long)(C >> 64); // bits 64..70

    __syncthreads();   // sW1 ready

    // Matvec: lane owns hidden unit `lane`. sW1[t*64+lane] is lane-consecutive
    // (2 lanes/bank = free). Select-add instead of fma: bitwise identical.
    float acc = b1[lane];
    #pragma unroll
    for (int t = 0; t < 64; ++t) {
        const float wv = sW1[t * HID + lane];
        acc += ((clo >> t) & 1ull) ? wv : 0.0f;
    }
    #pragma unroll
    for (int t = 64; t < CTX; ++t) {
        const float wv = sW1[t * HID + lane];
        acc += ((chi >> (t - 64)) & 1ull) ? wv : 0.0f;
    }
    const float hv      = acc > 0.0f ? acc : 0.0f;
    float       contrib = hv * W2[lane];

    #pragma unroll
    for (int off = 32; off > 0; off >>= 1)
        contrib += __shfl_down(contrib, off);

    if (lane == 0) {
        const float logit = contrib + b2[0];
        const float pred  = logit > 0.0f ? 1.0f : 0.0f;
        sflag[wave] = (pred != actual) ? 1.0f : 0.0f;
    }
    __syncthreads();

    if (threadIdx.x == 0) {
        float blk = 0.0f;
        #pragma unroll
        for (int w = 0; w < NPB; ++w) blk += sflag[w];
        partial[blockIdx.x] = blk;
    }
}

// K2: single wave reduces 200 per-block partials (float4 loads) -> mean.
__global__ void __launch_bounds__(64)
le_reduce_kernel(const float* __restrict__ partial, float* __restrict__ out)
{
    const int tid = threadIdx.x;                 // 0..63
    float4 v = make_float4(0.f, 0.f, 0.f, 0.f);
    if (tid < NBLK / 4)                          // 50 float4s
        v = ((const float4*)partial)[tid];
    float ssum = (v.x + v.y) + (v.z + v.w);

    #pragma unroll
    for (int off = 32; off > 0; off >>= 1)
        ssum += __shfl_down(ssum, off);

    if (tid == 0) out[0] = ssum * (1.0f / (float)(BB * SS));
}

extern "C" void kernel_launch(void* const* d_in, const int* in_sizes, int n_in,
                              void* d_out, int out_size, void* d_ws, size_t ws_size,
                              hipStream_t stream)
{
    const float* z     = (const float*)d_in[0];
    const float* W1    = (const float*)d_in[1];
    const float* b1    = (const float*)d_in[2];
    const float* W2    = (const float*)d_in[3];
    const float* b2    = (const float*)d_in[4];
    const int*   b_idx = (const int*)d_in[5];
    const int*   i_idx = (const int*)d_in[6];
    const int*   j_idx = (const int*)d_in[7];

    float* out     = (float*)d_out;
    float* partial = (float*)d_ws;               // NBLK floats = 800 B

    le_core_kernel<<<NBLK, TPB, 0, stream>>>(z, W1, b1, W2, b2,
                                             b_idx, i_idx, j_idx, partial);
    le_reduce_kernel<<<1, 64, 0, stream>>>(partial, out);
}

// Round 8
// 10.872 us; speedup vs baseline: 4.8732x; 1.0038x over previous
//
#include <hip/hip_runtime.h>

// Problem constants from the reference (fixed problem instance).
#define BB 32      // batch
#define KK 8       // channels
#define HH 512     // height
#define WW 512     // width
#define SS 50      // sample count
#define HID 64     // hidden dim
#define CTX 71     // 9*K - 1

#define NPB  8                   // pairs (waves) per block
#define TPB  (NPB * 64)          // 512 threads
#define NBLK (BB * SS / NPB)     // 200 blocks -> at most 1 block per CU

// K1: 8 (b,s) pairs per 512-thread block, one block per CU.
// z in {0,1} -> context captured as a wave-uniform 72-bit mask via __ballot.
// Matvec = 71 x { conflict-free ds_read_b32 + mask-selected add }, split
// across 4 accumulators to shorten the dependent-add chain.
__global__ void __launch_bounds__(TPB)
le_core_kernel(const float* __restrict__ z,
               const float* __restrict__ W1,
               const float* __restrict__ b1,
               const float* __restrict__ W2,
               const float* __restrict__ b2,
               const int*   __restrict__ b_idx,
               const int*   __restrict__ i_idx,
               const int*   __restrict__ j_idx,
               float*       __restrict__ partial)
{
    const int wave = threadIdx.x >> 6;           // 0..7
    const int lane = threadIdx.x & 63;           // 0..63
    const int bs   = blockIdx.x * NPB + wave;    // 0..1599
    const int b    = bs / SS;
    const int s    = bs - b * SS;

    __shared__ float sW1[CTX * HID];             // 18176 B, shared by 8 waves
    __shared__ float sflag[NPB];

    // Wave-uniform sample indices.
    const int i0 = i_idx[s];
    const int j0 = j_idx[s];
    const int rm = 4 * KK + b_idx[s];            // removed position, in [32,39]

    // Hoisted small loads: latency hides under the z gather below.
    const float bias1 = b1[lane];
    const float w2h   = W2[lane];
    const float bias2 = b2[0];

    // Scattered z gather straight into registers (HBM latency ~900 cy).
    // Lane p holds neighborhood position p = n*KK + k; lanes 0..7 also 64+p.
    float z0, z1 = 0.0f;
    {
        const int n  = lane >> 3;
        const int k  = lane & 7;
        const int ni = (i0 + (n / 3) - 1) & (HH - 1);   // torus wrap
        const int nj = (j0 + (n % 3) - 1) & (WW - 1);
        z0 = z[(((b * KK + k) * HH + ni) * WW) + nj];
    }
    if (lane < 8) {
        const int ni = (i0 + 1) & (HH - 1);
        const int nj = (j0 + 1) & (WW - 1);
        z1 = z[(((b * KK + lane) * HH + ni) * WW) + nj];
    }

    // Cooperative W1 -> LDS staging (float4); flies concurrently with gather.
    {
        const float4* s4 = (const float4*)W1;
        float4*       d4 = (float4*)sW1;
        #pragma unroll
        for (int idx = threadIdx.x; idx < (CTX * HID) / 4; idx += TPB)
            d4[idx] = s4[idx];
    }

    // Context as a 72-bit wave-uniform mask.
    const unsigned long long mlo = __ballot(z0 > 0.5f);           // bits 0..63
    const unsigned long long mhi = __ballot(z1 > 0.5f) & 0xFFull; // bits 64..71

    const float actual = (float)((unsigned)(mlo >> rm) & 1u);     // rm < 64

    // Remove bit rm, shift upper bits down: 71-bit compressed mask.
    const unsigned __int128 M  = ((unsigned __int128)mhi << 64) | mlo;
    const unsigned __int128 lo = M & ((((unsigned __int128)1) << rm) - 1);
    const unsigned __int128 C  = lo | ((M >> (rm + 1)) << rm);
    const unsigned long long clo = (unsigned long long)C;
    const unsigned long long chi = (unsigned long long)(C >> 64); // bits 64..70

    __syncthreads();   // sW1 ready

    // Matvec: lane owns hidden unit `lane`. sW1[t*64+lane] is lane-consecutive
    // (2 lanes/bank = free). 4 accumulators break the dependent-add chain.
    float a0 = bias1, a1 = 0.0f, a2 = 0.0f, a3 = 0.0f;
    #pragma unroll
    for (int t = 0; t < 64; t += 4) {
        a0 += ((clo >> (t + 0)) & 1ull) ? sW1[(t + 0) * HID + lane] : 0.0f;
        a1 += ((clo >> (t + 1)) & 1ull) ? sW1[(t + 1) * HID + lane] : 0.0f;
        a2 += ((clo >> (t + 2)) & 1ull) ? sW1[(t + 2) * HID + lane] : 0.0f;
        a3 += ((clo >> (t + 3)) & 1ull) ? sW1[(t + 3) * HID + lane] : 0.0f;
    }
    #pragma unroll
    for (int t = 64; t < CTX; ++t) {
        const int q = t & 3;
        const float wv = sW1[t * HID + lane];
        const float sel = ((chi >> (t - 64)) & 1ull) ? wv : 0.0f;
        if (q == 0) a0 += sel; else if (q == 1) a1 += sel;
        else if (q == 2) a2 += sel; else a3 += sel;
    }
    const float acc     = (a0 + a1) + (a2 + a3);
    const float hv      = acc > 0.0f ? acc : 0.0f;
    float       contrib = hv * w2h;

    #pragma unroll
    for (int off = 32; off > 0; off >>= 1)
        contrib += __shfl_down(contrib, off);

    if (lane == 0) {
        const float logit = contrib + bias2;
        const float pred  = logit > 0.0f ? 1.0f : 0.0f;
        sflag[wave] = (pred != actual) ? 1.0f : 0.0f;
    }
    __syncthreads();

    if (threadIdx.x == 0) {
        float blk = 0.0f;
        #pragma unroll
        for (int w = 0; w < NPB; ++w) blk += sflag[w];
        partial[blockIdx.x] = blk;
    }
}

// K2: single wave reduces 200 per-block partials (float4 loads) -> mean.
__global__ void __launch_bounds__(64)
le_reduce_kernel(const float* __restrict__ partial, float* __restrict__ out)
{
    const int tid = threadIdx.x;                 // 0..63
    float4 v = make_float4(0.f, 0.f, 0.f, 0.f);
    if (tid < NBLK / 4)                          // 50 float4s
        v = ((const float4*)partial)[tid];
    float ssum = (v.x + v.y) + (v.z + v.w);

    #pragma unroll
    for (int off = 32; off > 0; off >>= 1)
        ssum += __shfl_down(ssum, off);

    if (tid == 0) out[0] = ssum * (1.0f / (float)(BB * SS));
}

extern "C" void kernel_launch(void* const* d_in, const int* in_sizes, int n_in,
                              void* d_out, int out_size, void* d_ws, size_t ws_size,
                              hipStream_t stream)
{
    const float* z     = (const float*)d_in[0];
    const float* W1    = (const float*)d_in[1];
    const float* b1    = (const float*)d_in[2];
    const float* W2    = (const float*)d_in[3];
    const float* b2    = (const float*)d_in[4];
    const int*   b_idx = (const int*)d_in[5];
    const int*   i_idx = (const int*)d_in[6];
    const int*   j_idx = (const int*)d_in[7];

    float* out     = (float*)d_out;
    float* partial = (float*)d_ws;               // NBLK floats = 800 B

    le_core_kernel<<<NBLK, TPB, 0, stream>>>(z, W1, b1, W2, b2,
                                             b_idx, i_idx, j_idx, partial);
    le_reduce_kernel<<<1, 64, 0, stream>>>(partial, out);
}